// Round 11
// baseline (807.525 us; speedup 1.0000x reference)
//
#include <hip/hip_runtime.h>

#define HIST_BITS 12
#define NBINS (1 << HIST_BITS)        // 4096
#define KEY_SHIFT (32 - HIST_BITS)    // 20
#define REP 4                         // LDS histogram replication factor
#define HGRID 512
#define HBLK 1024
#define AGRID 2048
#define ABLK 256

typedef float fx4 __attribute__((ext_vector_type(4)));

// ws layout:
//   [0, 16384)     : unsigned hist[4096]
//   [16384, 16432) : Ctrl
//   [16448, ...)   : uint2 candidate list (key, idx)
struct Ctrl {
    long long k;        // number of elements to zero
    long long r1;       // residual rank inside threshold bin (zero first r1)
    int b1;             // threshold bin (-1 => zero nothing)
    unsigned counter;   // candidate list append counter
    unsigned arrive1;   // hist block-arrival counter
    unsigned arrive2;   // apply block-arrival counter
};

__device__ __forceinline__ unsigned fkey(float f) {
    unsigned u = __float_as_uint(f);
    return (u & 0x80000000u) ? ~u : (u | 0x80000000u);  // monotonic total order
}

// ---------------- K0: zero hist + ctrl ----------------
__global__ void k_zero(unsigned* __restrict__ hist, Ctrl* __restrict__ ctrl) {
    int i = blockIdx.x * blockDim.x + threadIdx.x;
    if (i < NBINS) hist[i] = 0;
    if (i == 0) {
        ctrl->k = 0; ctrl->r1 = 0; ctrl->b1 = -1;
        ctrl->counter = 0; ctrl->arrive1 = 0; ctrl->arrive2 = 0;
    }
}

// ---------------- K1: histogram + last-block scan (deadlock-free) ----------------
// NOTE: no min-waves in launch_bounds — R8/R10 proved the min-waves arg squeezes
// VGPRs (32) and serializes the ILP loop. Compiler's natural allocation wins.
__global__ void __launch_bounds__(HBLK)
k_hist(const float* __restrict__ mask, long long n, unsigned* __restrict__ ghist,
       Ctrl* __restrict__ ctrl, const float* __restrict__ p_ptr) {
    __shared__ unsigned sh[NBINS * REP];   // 64 KB (scan part[] aliases after flush)
    __shared__ int s_last;
    const int tid = threadIdx.x;
    if (tid == 0) s_last = 0;
    for (int i = tid; i < NBINS * REP; i += HBLK) sh[i] = 0;
    __syncthreads();

    const long long n4 = n >> 2;
    const fx4* m4 = (const fx4*)mask;
    const long long B = HBLK;
    const long long per = (n4 + gridDim.x - 1) / gridDim.x;   // contiguous tile per block
    const long long s0 = (long long)blockIdx.x * per;
    const long long e = (s0 + per < n4) ? s0 + per : n4;

    const unsigned r = tid & (REP - 1);
    long long i = s0 + tid;
    for (; i + 3 * B < e; i += 4 * B) {
        fx4 a = m4[i];
        fx4 b = m4[i + B];
        fx4 c = m4[i + 2 * B];
        fx4 d = m4[i + 3 * B];
        atomicAdd(&sh[(fkey(a.x) >> KEY_SHIFT) * REP + r], 1u);
        atomicAdd(&sh[(fkey(a.y) >> KEY_SHIFT) * REP + r], 1u);
        atomicAdd(&sh[(fkey(a.z) >> KEY_SHIFT) * REP + r], 1u);
        atomicAdd(&sh[(fkey(a.w) >> KEY_SHIFT) * REP + r], 1u);
        atomicAdd(&sh[(fkey(b.x) >> KEY_SHIFT) * REP + r], 1u);
        atomicAdd(&sh[(fkey(b.y) >> KEY_SHIFT) * REP + r], 1u);
        atomicAdd(&sh[(fkey(b.z) >> KEY_SHIFT) * REP + r], 1u);
        atomicAdd(&sh[(fkey(b.w) >> KEY_SHIFT) * REP + r], 1u);
        atomicAdd(&sh[(fkey(c.x) >> KEY_SHIFT) * REP + r], 1u);
        atomicAdd(&sh[(fkey(c.y) >> KEY_SHIFT) * REP + r], 1u);
        atomicAdd(&sh[(fkey(c.z) >> KEY_SHIFT) * REP + r], 1u);
        atomicAdd(&sh[(fkey(c.w) >> KEY_SHIFT) * REP + r], 1u);
        atomicAdd(&sh[(fkey(d.x) >> KEY_SHIFT) * REP + r], 1u);
        atomicAdd(&sh[(fkey(d.y) >> KEY_SHIFT) * REP + r], 1u);
        atomicAdd(&sh[(fkey(d.z) >> KEY_SHIFT) * REP + r], 1u);
        atomicAdd(&sh[(fkey(d.w) >> KEY_SHIFT) * REP + r], 1u);
    }
    for (; i < e; i += B) {
        fx4 a = m4[i];
        atomicAdd(&sh[(fkey(a.x) >> KEY_SHIFT) * REP + r], 1u);
        atomicAdd(&sh[(fkey(a.y) >> KEY_SHIFT) * REP + r], 1u);
        atomicAdd(&sh[(fkey(a.z) >> KEY_SHIFT) * REP + r], 1u);
        atomicAdd(&sh[(fkey(a.w) >> KEY_SHIFT) * REP + r], 1u);
    }
    if (blockIdx.x == 0 && tid == 0) {             // n%4 tail
        for (long long t = n4 * 4; t < n; ++t)
            atomicAdd(&ghist[fkey(mask[t]) >> KEY_SHIFT], 1u);
    }
    __syncthreads();
    for (int b = tid; b < NBINS; b += HBLK) {
        unsigned s = sh[b * REP] + sh[b * REP + 1] + sh[b * REP + 2] + sh[b * REP + 3];
        if (s) atomicAdd(&ghist[b], s);
    }
    __threadfence();                               // release my hist adds

    if (tid == 0) {
        unsigned old = __hip_atomic_fetch_add(&ctrl->arrive1, 1u,
                                              __ATOMIC_ACQ_REL, __HIP_MEMORY_SCOPE_AGENT);
        if (old == gridDim.x - 1) s_last = 1;
    }
    __syncthreads();
    if (!s_last) return;                            // all but the last block exit — no waiting
    __threadfence();                                // acquire all blocks' hist adds

    // ---- last block: scan 4096 bins, find threshold ----
    long long* part = (long long*)sh;               // hist LDS retired; alias for scan
    double p = (double)p_ptr[0];
    long long kk = (long long)((1.0 - p) * (double)n);  // matches python int()
    if (kk < 0) kk = 0;
    if (kk > n) kk = n;
    const int pern = NBINS / HBLK;                  // 4 bins per thread
    unsigned cs[pern];
    long long s = 0;
    #pragma unroll
    for (int q = 0; q < pern; ++q) {
        cs[q] = __hip_atomic_load(&ghist[tid * pern + q], __ATOMIC_RELAXED, __HIP_MEMORY_SCOPE_AGENT);
        s += (long long)cs[q];
    }
    part[tid] = s;
    __syncthreads();
    for (int off = 1; off < HBLK; off <<= 1) {      // Hillis-Steele inclusive scan
        long long add = (tid >= off) ? part[tid - off] : 0;
        __syncthreads();
        part[tid] += add;
        __syncthreads();
    }
    if (kk >= 1) {
        long long incl = part[tid];
        long long excl = incl - s;
        if (excl < kk && kk <= incl) {
            long long cum = excl;
            #pragma unroll
            for (int q = 0; q < pern; ++q) {
                long long c = (long long)cs[q];
                if (cum < kk && kk <= cum + c) {
                    ctrl->b1 = tid * pern + q;
                    ctrl->r1 = kk - cum;            // kernel boundary publishes
                    break;
                }
                cum += c;
            }
        }
    }
}

// ---------------- K2: apply + candidates + last-block fix (deadlock-free) ----------------
__global__ void __launch_bounds__(ABLK)
k_apply(const float* __restrict__ w, const float* __restrict__ mask,
        float* __restrict__ out, long long n,
        Ctrl* __restrict__ ctrl, uint2* __restrict__ list, unsigned cap) {
    __shared__ uint2 ch[1024];                      // fix-phase chunk buffer (8 KB)
    __shared__ int s_last;
    const int tid = threadIdx.x;
    if (tid == 0) s_last = 0;

    const int b1 = ctrl->b1;
    const unsigned b1u = (unsigned)b1;                                  // never matches for b1=-1
    const unsigned lo = (b1 <= 0) ? 0u : ((unsigned)b1 << KEY_SHIFT);   // keep iff key >= lo
    const long long n4 = n >> 2;
    const fx4* m4 = (const fx4*)mask;
    const fx4* w4 = (const fx4*)w;
    fx4* o4 = (fx4*)out;
    const long long B = ABLK;
    const long long per = (n4 + gridDim.x - 1) / gridDim.x;   // contiguous tile per block
    const long long s0 = (long long)blockIdx.x * per;
    const long long e = (s0 + per < n4) ? s0 + per : n4;

    long long i = s0 + tid;
    for (; i + 3 * B < e; i += 4 * B) {
        fx4 m0 = m4[i];
        fx4 m1 = m4[i + B];
        fx4 m2 = m4[i + 2 * B];
        fx4 m3 = m4[i + 3 * B];
        fx4 w0 = __builtin_nontemporal_load(&w4[i]);
        fx4 w1 = __builtin_nontemporal_load(&w4[i + B]);
        fx4 w2 = __builtin_nontemporal_load(&w4[i + 2 * B]);
        fx4 w3 = __builtin_nontemporal_load(&w4[i + 3 * B]);
        unsigned k00 = fkey(m0.x), k01 = fkey(m0.y), k02 = fkey(m0.z), k03 = fkey(m0.w);
        unsigned k10 = fkey(m1.x), k11 = fkey(m1.y), k12 = fkey(m1.z), k13 = fkey(m1.w);
        unsigned k20 = fkey(m2.x), k21 = fkey(m2.y), k22 = fkey(m2.z), k23 = fkey(m2.w);
        unsigned k30 = fkey(m3.x), k31 = fkey(m3.y), k32 = fkey(m3.z), k33 = fkey(m3.w);
        fx4 o0, o1, o2, o3;
        o0.x = (k00 >= lo) ? w0.x : 0.0f;  o0.y = (k01 >= lo) ? w0.y : 0.0f;
        o0.z = (k02 >= lo) ? w0.z : 0.0f;  o0.w = (k03 >= lo) ? w0.w : 0.0f;
        o1.x = (k10 >= lo) ? w1.x : 0.0f;  o1.y = (k11 >= lo) ? w1.y : 0.0f;
        o1.z = (k12 >= lo) ? w1.z : 0.0f;  o1.w = (k13 >= lo) ? w1.w : 0.0f;
        o2.x = (k20 >= lo) ? w2.x : 0.0f;  o2.y = (k21 >= lo) ? w2.y : 0.0f;
        o2.z = (k22 >= lo) ? w2.z : 0.0f;  o2.w = (k23 >= lo) ? w2.w : 0.0f;
        o3.x = (k30 >= lo) ? w3.x : 0.0f;  o3.y = (k31 >= lo) ? w3.y : 0.0f;
        o3.z = (k32 >= lo) ? w3.z : 0.0f;  o3.w = (k33 >= lo) ? w3.w : 0.0f;
        __builtin_nontemporal_store(o0, &o4[i]);
        __builtin_nontemporal_store(o1, &o4[i + B]);
        __builtin_nontemporal_store(o2, &o4[i + 2 * B]);
        __builtin_nontemporal_store(o3, &o4[i + 3 * B]);
        bool anyc = ((k00 >> KEY_SHIFT) == b1u) | ((k01 >> KEY_SHIFT) == b1u) |
                    ((k02 >> KEY_SHIFT) == b1u) | ((k03 >> KEY_SHIFT) == b1u) |
                    ((k10 >> KEY_SHIFT) == b1u) | ((k11 >> KEY_SHIFT) == b1u) |
                    ((k12 >> KEY_SHIFT) == b1u) | ((k13 >> KEY_SHIFT) == b1u) |
                    ((k20 >> KEY_SHIFT) == b1u) | ((k21 >> KEY_SHIFT) == b1u) |
                    ((k22 >> KEY_SHIFT) == b1u) | ((k23 >> KEY_SHIFT) == b1u) |
                    ((k30 >> KEY_SHIFT) == b1u) | ((k31 >> KEY_SHIFT) == b1u) |
                    ((k32 >> KEY_SHIFT) == b1u) | ((k33 >> KEY_SHIFT) == b1u);
        if (__any(anyc)) {   // rare path
            unsigned ks[16] = {k00,k01,k02,k03,k10,k11,k12,k13,k20,k21,k22,k23,k30,k31,k32,k33};
            long long bases[4] = {i, i + B, i + 2 * B, i + 3 * B};
            #pragma unroll
            for (int q = 0; q < 4; ++q)
                #pragma unroll
                for (int j = 0; j < 4; ++j)
                    if ((ks[q * 4 + j] >> KEY_SHIFT) == b1u) {
                        unsigned p = atomicAdd(&ctrl->counter, 1u);
                        if (p < cap) list[p] = make_uint2(ks[q * 4 + j], (unsigned)(bases[q] * 4 + j));
                    }
        }
    }
    for (; i < e; i += B) {
        fx4 m0 = m4[i];
        fx4 w0 = __builtin_nontemporal_load(&w4[i]);
        unsigned k00 = fkey(m0.x), k01 = fkey(m0.y), k02 = fkey(m0.z), k03 = fkey(m0.w);
        fx4 o0;
        o0.x = (k00 >= lo) ? w0.x : 0.0f;  o0.y = (k01 >= lo) ? w0.y : 0.0f;
        o0.z = (k02 >= lo) ? w0.z : 0.0f;  o0.w = (k03 >= lo) ? w0.w : 0.0f;
        __builtin_nontemporal_store(o0, &o4[i]);
        bool anyc = ((k00 >> KEY_SHIFT) == b1u) | ((k01 >> KEY_SHIFT) == b1u) |
                    ((k02 >> KEY_SHIFT) == b1u) | ((k03 >> KEY_SHIFT) == b1u);
        if (__any(anyc)) {
            unsigned ks[4] = {k00, k01, k02, k03};
            #pragma unroll
            for (int j = 0; j < 4; ++j)
                if ((ks[j] >> KEY_SHIFT) == b1u) {
                    unsigned p = atomicAdd(&ctrl->counter, 1u);
                    if (p < cap) list[p] = make_uint2(ks[j], (unsigned)(i * 4 + j));
                }
        }
    }
    if (blockIdx.x == 0 && tid == 0) {             // n%4 tail
        for (long long t = n4 * 4; t < n; ++t) {
            unsigned key = fkey(mask[t]);
            out[t] = (key >= lo) ? w[t] : 0.0f;
            if ((key >> KEY_SHIFT) == b1u) {
                unsigned p = atomicAdd(&ctrl->counter, 1u);
                if (p < cap) list[p] = make_uint2(key, (unsigned)t);
            }
        }
    }

    __threadfence();                                // release my out/list/counter writes
    if (tid == 0) {
        unsigned old = __hip_atomic_fetch_add(&ctrl->arrive2, 1u,
                                              __ATOMIC_ACQ_REL, __HIP_MEMORY_SCOPE_AGENT);
        if (old == gridDim.x - 1) s_last = 1;
    }
    __syncthreads();
    if (!s_last) return;                            // no block waits
    __threadfence();                                // acquire all blocks' writes

    // ---- last block: exact rank among candidates, zero first r1 ----
    unsigned nc = __hip_atomic_load(&ctrl->counter, __ATOMIC_RELAXED, __HIP_MEMORY_SCOPE_AGENT);
    if (nc > cap) nc = cap;
    const long long r1 = ctrl->r1;
    if (b1 < 0 || r1 <= 0) return;

    for (unsigned jb = 0; jb < nc; jb += ABLK) {
        unsigned j = jb + tid;
        bool act = (j < nc);
        unsigned kj = 0, ij = 0;
        if (act) { uint2 ee = list[j]; kj = ee.x; ij = ee.y; }
        long long rank = 0;
        for (unsigned cb = 0; cb < nc; cb += 1024) {
            unsigned mlen = nc - cb; if (mlen > 1024) mlen = 1024;
            for (unsigned u = tid; u < mlen; u += ABLK) ch[u] = list[cb + u];
            __syncthreads();
            if (act) {
                for (unsigned u = 0; u < mlen; ++u) {
                    uint2 ee = ch[u];
                    rank += (long long)((ee.x < kj) || (ee.x == kj && ee.y < ij));
                }
            }
            __syncthreads();
        }
        if (act && rank < r1) out[ij] = 0.0f;
    }
}

extern "C" void kernel_launch(void* const* d_in, const int* in_sizes, int n_in,
                              void* d_out, int out_size, void* d_ws, size_t ws_size,
                              hipStream_t stream) {
    const float* weight = (const float*)d_in[0];
    const float* maskw  = (const float*)d_in[1];
    const float* pptr   = (const float*)d_in[2];
    float* out = (float*)d_out;
    const long long n = (long long)in_sizes[0];

    unsigned char* ws = (unsigned char*)d_ws;
    unsigned* hist = (unsigned*)ws;
    Ctrl* ctrl = (Ctrl*)(ws + 16384);
    uint2* list = (uint2*)(ws + 16448);
    size_t cap_sz = (ws_size > 16448) ? (ws_size - 16448) / sizeof(uint2) : 0;
    unsigned cap = (unsigned)(cap_sz > (size_t)(1u << 20) ? (1u << 20) : cap_sz);

    k_zero<<<(NBINS + 255) / 256, 256, 0, stream>>>(hist, ctrl);
    k_hist<<<HGRID, HBLK, 0, stream>>>(maskw, n, hist, ctrl, pptr);
    k_apply<<<AGRID, ABLK, 0, stream>>>(weight, maskw, out, n, ctrl, list, cap);
}

// Round 13
// 344.232 us; speedup vs baseline: 2.3459x; 2.3459x over previous
//
#include <hip/hip_runtime.h>

#define HIST_BITS 12
#define NBINS (1 << HIST_BITS)        // 4096
#define KEY_SHIFT (32 - HIST_BITS)    // 20
#define REP 4                         // LDS histogram replication factor
#define HGRID 512
#define HBLK 1024
#define AGRID 2048
#define ABLK 256

typedef float fx4 __attribute__((ext_vector_type(4)));

// ws layout:
//   [0, 16384)     : unsigned hist[4096]
//   [16384, 16432) : Ctrl
//   [16448, ...)   : uint2 candidate list (key, idx)
struct Ctrl {
    long long k;        // number of elements to zero
    long long r1;       // residual rank inside threshold bin (zero first r1)
    int b1;             // threshold bin (-1 => zero nothing)
    unsigned counter;   // candidate list append counter
    unsigned arrive1;   // hist block-arrival counter
    unsigned arrive2;   // (unused)
};

__device__ __forceinline__ unsigned fkey(float f) {
    unsigned u = __float_as_uint(f);
    return (u & 0x80000000u) ? ~u : (u | 0x80000000u);  // monotonic total order
}

// ---------------- K0: zero hist + ctrl ----------------
__global__ void k_zero(unsigned* __restrict__ hist, Ctrl* __restrict__ ctrl) {
    int i = blockIdx.x * blockDim.x + threadIdx.x;
    if (i < NBINS) hist[i] = 0;
    if (i == 0) {
        ctrl->k = 0; ctrl->r1 = 0; ctrl->b1 = -1;
        ctrl->counter = 0; ctrl->arrive1 = 0; ctrl->arrive2 = 0;
    }
}

// ---------------- K1: histogram + last-block scan (deadlock-free) ----------------
// Hist loop identical to R7's proven kernel; after flushing, blocks exit and only
// the last arrival scans (no spinning). LDS epilogue is fine HERE: the hist body
// already uses LDS heavily and is DS-pipe-bound, not register-bound.
__global__ void __launch_bounds__(HBLK)
k_hist(const float* __restrict__ mask, long long n, unsigned* __restrict__ ghist,
       Ctrl* __restrict__ ctrl, const float* __restrict__ p_ptr) {
    __shared__ unsigned sh[NBINS * REP];   // 64 KB (scan part[] aliases after flush)
    __shared__ int s_last;
    const int tid = threadIdx.x;
    if (tid == 0) s_last = 0;
    for (int i = tid; i < NBINS * REP; i += HBLK) sh[i] = 0;
    __syncthreads();

    const long long n4 = n >> 2;
    const fx4* m4 = (const fx4*)mask;
    const long long B = HBLK;
    const long long per = (n4 + gridDim.x - 1) / gridDim.x;   // contiguous tile per block
    const long long s0 = (long long)blockIdx.x * per;
    const long long e = (s0 + per < n4) ? s0 + per : n4;

    const unsigned r = tid & (REP - 1);
    long long i = s0 + tid;
    for (; i + 3 * B < e; i += 4 * B) {
        fx4 a = m4[i];
        fx4 b = m4[i + B];
        fx4 c = m4[i + 2 * B];
        fx4 d = m4[i + 3 * B];
        atomicAdd(&sh[(fkey(a.x) >> KEY_SHIFT) * REP + r], 1u);
        atomicAdd(&sh[(fkey(a.y) >> KEY_SHIFT) * REP + r], 1u);
        atomicAdd(&sh[(fkey(a.z) >> KEY_SHIFT) * REP + r], 1u);
        atomicAdd(&sh[(fkey(a.w) >> KEY_SHIFT) * REP + r], 1u);
        atomicAdd(&sh[(fkey(b.x) >> KEY_SHIFT) * REP + r], 1u);
        atomicAdd(&sh[(fkey(b.y) >> KEY_SHIFT) * REP + r], 1u);
        atomicAdd(&sh[(fkey(b.z) >> KEY_SHIFT) * REP + r], 1u);
        atomicAdd(&sh[(fkey(b.w) >> KEY_SHIFT) * REP + r], 1u);
        atomicAdd(&sh[(fkey(c.x) >> KEY_SHIFT) * REP + r], 1u);
        atomicAdd(&sh[(fkey(c.y) >> KEY_SHIFT) * REP + r], 1u);
        atomicAdd(&sh[(fkey(c.z) >> KEY_SHIFT) * REP + r], 1u);
        atomicAdd(&sh[(fkey(c.w) >> KEY_SHIFT) * REP + r], 1u);
        atomicAdd(&sh[(fkey(d.x) >> KEY_SHIFT) * REP + r], 1u);
        atomicAdd(&sh[(fkey(d.y) >> KEY_SHIFT) * REP + r], 1u);
        atomicAdd(&sh[(fkey(d.z) >> KEY_SHIFT) * REP + r], 1u);
        atomicAdd(&sh[(fkey(d.w) >> KEY_SHIFT) * REP + r], 1u);
    }
    for (; i < e; i += B) {
        fx4 a = m4[i];
        atomicAdd(&sh[(fkey(a.x) >> KEY_SHIFT) * REP + r], 1u);
        atomicAdd(&sh[(fkey(a.y) >> KEY_SHIFT) * REP + r], 1u);
        atomicAdd(&sh[(fkey(a.z) >> KEY_SHIFT) * REP + r], 1u);
        atomicAdd(&sh[(fkey(a.w) >> KEY_SHIFT) * REP + r], 1u);
    }
    if (blockIdx.x == 0 && tid == 0) {             // n%4 tail
        for (long long t = n4 * 4; t < n; ++t)
            atomicAdd(&ghist[fkey(mask[t]) >> KEY_SHIFT], 1u);
    }
    __syncthreads();
    for (int b = tid; b < NBINS; b += HBLK) {
        unsigned s = sh[b * REP] + sh[b * REP + 1] + sh[b * REP + 2] + sh[b * REP + 3];
        if (s) atomicAdd(&ghist[b], s);
    }
    __threadfence();                               // release my hist adds

    if (tid == 0) {
        unsigned old = __hip_atomic_fetch_add(&ctrl->arrive1, 1u,
                                              __ATOMIC_ACQ_REL, __HIP_MEMORY_SCOPE_AGENT);
        if (old == gridDim.x - 1) s_last = 1;
    }
    __syncthreads();
    if (!s_last) return;                            // all but the last block exit — no waiting
    __threadfence();                                // acquire all blocks' hist adds

    // ---- last block: scan 4096 bins, find threshold ----
    long long* part = (long long*)sh;               // hist LDS retired; alias for scan
    double p = (double)p_ptr[0];
    long long kk = (long long)((1.0 - p) * (double)n);  // matches python int()
    if (kk < 0) kk = 0;
    if (kk > n) kk = n;
    const int pern = NBINS / HBLK;                  // 4 bins per thread
    unsigned cs[pern];
    long long s = 0;
    #pragma unroll
    for (int q = 0; q < pern; ++q) {
        cs[q] = __hip_atomic_load(&ghist[tid * pern + q], __ATOMIC_RELAXED, __HIP_MEMORY_SCOPE_AGENT);
        s += (long long)cs[q];
    }
    part[tid] = s;
    __syncthreads();
    for (int off = 1; off < HBLK; off <<= 1) {      // Hillis-Steele inclusive scan
        long long add = (tid >= off) ? part[tid - off] : 0;
        __syncthreads();
        part[tid] += add;
        __syncthreads();
    }
    if (kk >= 1) {
        long long incl = part[tid];
        long long excl = incl - s;
        if (excl < kk && kk <= incl) {
            long long cum = excl;
            #pragma unroll
            for (int q = 0; q < pern; ++q) {
                long long c = (long long)cs[q];
                if (cum < kk && kk <= cum + c) {
                    ctrl->b1 = tid * pern + q;
                    ctrl->r1 = kk - cum;            // kernel boundary publishes
                    break;
                }
                cum += c;
            }
        }
    }
}

// ---------------- K2: fused apply + candidate collection (R7 verbatim) ----------------
// NO __shared__, NO epilogue here: R10/R11 proved an LDS epilogue in this kernel
// makes the backend cap VGPRs at 32 and serialize the ILP4 loop (595us vs ~140us).
__device__ __forceinline__ void cand4(unsigned k0, unsigned k1, unsigned k2, unsigned k3,
                                      unsigned base, unsigned b1u,
                                      Ctrl* ctrl, uint2* list, unsigned cap) {
    if ((k0 >> KEY_SHIFT) == b1u) { unsigned p = atomicAdd(&ctrl->counter, 1u); if (p < cap) list[p] = make_uint2(k0, base + 0); }
    if ((k1 >> KEY_SHIFT) == b1u) { unsigned p = atomicAdd(&ctrl->counter, 1u); if (p < cap) list[p] = make_uint2(k1, base + 1); }
    if ((k2 >> KEY_SHIFT) == b1u) { unsigned p = atomicAdd(&ctrl->counter, 1u); if (p < cap) list[p] = make_uint2(k2, base + 2); }
    if ((k3 >> KEY_SHIFT) == b1u) { unsigned p = atomicAdd(&ctrl->counter, 1u); if (p < cap) list[p] = make_uint2(k3, base + 3); }
}

__global__ void __launch_bounds__(ABLK)
k_apply(const float* __restrict__ w, const float* __restrict__ mask,
        float* __restrict__ out, long long n,
        Ctrl* __restrict__ ctrl, uint2* __restrict__ list, unsigned cap) {
    const int b1 = ctrl->b1;
    const unsigned b1u = (unsigned)b1;                                  // never matches for b1=-1
    const unsigned lo = (b1 <= 0) ? 0u : ((unsigned)b1 << KEY_SHIFT);   // keep iff key >= lo
    const long long n4 = n >> 2;
    const fx4* m4 = (const fx4*)mask;
    const fx4* w4 = (const fx4*)w;
    fx4* o4 = (fx4*)out;
    const long long B = ABLK;
    const long long per = (n4 + gridDim.x - 1) / gridDim.x;   // contiguous tile per block
    const long long s0 = (long long)blockIdx.x * per;
    const long long e = (s0 + per < n4) ? s0 + per : n4;

    long long i = s0 + threadIdx.x;
    for (; i + 3 * B < e; i += 4 * B) {
        fx4 m0 = m4[i];
        fx4 m1 = m4[i + B];
        fx4 m2 = m4[i + 2 * B];
        fx4 m3 = m4[i + 3 * B];
        fx4 w0 = __builtin_nontemporal_load(&w4[i]);
        fx4 w1 = __builtin_nontemporal_load(&w4[i + B]);
        fx4 w2 = __builtin_nontemporal_load(&w4[i + 2 * B]);
        fx4 w3 = __builtin_nontemporal_load(&w4[i + 3 * B]);
        unsigned k00 = fkey(m0.x), k01 = fkey(m0.y), k02 = fkey(m0.z), k03 = fkey(m0.w);
        unsigned k10 = fkey(m1.x), k11 = fkey(m1.y), k12 = fkey(m1.z), k13 = fkey(m1.w);
        unsigned k20 = fkey(m2.x), k21 = fkey(m2.y), k22 = fkey(m2.z), k23 = fkey(m2.w);
        unsigned k30 = fkey(m3.x), k31 = fkey(m3.y), k32 = fkey(m3.z), k33 = fkey(m3.w);
        fx4 o0, o1, o2, o3;
        o0.x = (k00 >= lo) ? w0.x : 0.0f;  o0.y = (k01 >= lo) ? w0.y : 0.0f;
        o0.z = (k02 >= lo) ? w0.z : 0.0f;  o0.w = (k03 >= lo) ? w0.w : 0.0f;
        o1.x = (k10 >= lo) ? w1.x : 0.0f;  o1.y = (k11 >= lo) ? w1.y : 0.0f;
        o1.z = (k12 >= lo) ? w1.z : 0.0f;  o1.w = (k13 >= lo) ? w1.w : 0.0f;
        o2.x = (k20 >= lo) ? w2.x : 0.0f;  o2.y = (k21 >= lo) ? w2.y : 0.0f;
        o2.z = (k22 >= lo) ? w2.z : 0.0f;  o2.w = (k23 >= lo) ? w2.w : 0.0f;
        o3.x = (k30 >= lo) ? w3.x : 0.0f;  o3.y = (k31 >= lo) ? w3.y : 0.0f;
        o3.z = (k32 >= lo) ? w3.z : 0.0f;  o3.w = (k33 >= lo) ? w3.w : 0.0f;
        __builtin_nontemporal_store(o0, &o4[i]);
        __builtin_nontemporal_store(o1, &o4[i + B]);
        __builtin_nontemporal_store(o2, &o4[i + 2 * B]);
        __builtin_nontemporal_store(o3, &o4[i + 3 * B]);
        bool anyc = ((k00 >> KEY_SHIFT) == b1u) | ((k01 >> KEY_SHIFT) == b1u) |
                    ((k02 >> KEY_SHIFT) == b1u) | ((k03 >> KEY_SHIFT) == b1u) |
                    ((k10 >> KEY_SHIFT) == b1u) | ((k11 >> KEY_SHIFT) == b1u) |
                    ((k12 >> KEY_SHIFT) == b1u) | ((k13 >> KEY_SHIFT) == b1u) |
                    ((k20 >> KEY_SHIFT) == b1u) | ((k21 >> KEY_SHIFT) == b1u) |
                    ((k22 >> KEY_SHIFT) == b1u) | ((k23 >> KEY_SHIFT) == b1u) |
                    ((k30 >> KEY_SHIFT) == b1u) | ((k31 >> KEY_SHIFT) == b1u) |
                    ((k32 >> KEY_SHIFT) == b1u) | ((k33 >> KEY_SHIFT) == b1u);
        if (__any(anyc)) {   // rare path
            cand4(k00, k01, k02, k03, (unsigned)(i * 4), b1u, ctrl, list, cap);
            cand4(k10, k11, k12, k13, (unsigned)((i + B) * 4), b1u, ctrl, list, cap);
            cand4(k20, k21, k22, k23, (unsigned)((i + 2 * B) * 4), b1u, ctrl, list, cap);
            cand4(k30, k31, k32, k33, (unsigned)((i + 3 * B) * 4), b1u, ctrl, list, cap);
        }
    }
    for (; i < e; i += B) {
        fx4 m0 = m4[i];
        fx4 w0 = __builtin_nontemporal_load(&w4[i]);
        unsigned k00 = fkey(m0.x), k01 = fkey(m0.y), k02 = fkey(m0.z), k03 = fkey(m0.w);
        fx4 o0;
        o0.x = (k00 >= lo) ? w0.x : 0.0f;  o0.y = (k01 >= lo) ? w0.y : 0.0f;
        o0.z = (k02 >= lo) ? w0.z : 0.0f;  o0.w = (k03 >= lo) ? w0.w : 0.0f;
        __builtin_nontemporal_store(o0, &o4[i]);
        bool anyc = ((k00 >> KEY_SHIFT) == b1u) | ((k01 >> KEY_SHIFT) == b1u) |
                    ((k02 >> KEY_SHIFT) == b1u) | ((k03 >> KEY_SHIFT) == b1u);
        if (__any(anyc))
            cand4(k00, k01, k02, k03, (unsigned)(i * 4), b1u, ctrl, list, cap);
    }
    if (blockIdx.x == 0 && threadIdx.x == 0) {     // n%4 tail
        for (long long t = n4 * 4; t < n; ++t) {
            unsigned key = fkey(mask[t]);
            out[t] = (key >= lo) ? w[t] : 0.0f;
            if ((key >> KEY_SHIFT) == b1u) {
                unsigned p = atomicAdd(&ctrl->counter, 1u);
                if (p < cap) list[p] = make_uint2(key, (unsigned)t);
            }
        }
    }
}

// ---------------- K3: exact rank among candidates, zero first r1 ----------------
__global__ void k_fix(float* __restrict__ out, const Ctrl* __restrict__ ctrl,
                      const uint2* __restrict__ list, unsigned cap) {
    __shared__ uint2 ch[1024];
    unsigned nc = ctrl->counter;
    if (nc > cap) nc = cap;
    const long long r1 = ctrl->r1;
    if (ctrl->b1 < 0 || r1 <= 0) return;

    for (unsigned jb = 0; jb < nc; jb += blockDim.x) {
        unsigned j = jb + threadIdx.x;
        bool act = (j < nc);
        unsigned kj = 0, ij = 0;
        if (act) { uint2 e = list[j]; kj = e.x; ij = e.y; }
        long long rank = 0;
        for (unsigned cb = 0; cb < nc; cb += 1024) {
            unsigned mlen = nc - cb; if (mlen > 1024) mlen = 1024;
            for (unsigned u = threadIdx.x; u < mlen; u += blockDim.x) ch[u] = list[cb + u];
            __syncthreads();
            if (act) {
                for (unsigned u = 0; u < mlen; ++u) {
                    uint2 e = ch[u];
                    rank += (long long)((e.x < kj) || (e.x == kj && e.y < ij));
                }
            }
            __syncthreads();
        }
        if (act && rank < r1) out[ij] = 0.0f;
    }
}

extern "C" void kernel_launch(void* const* d_in, const int* in_sizes, int n_in,
                              void* d_out, int out_size, void* d_ws, size_t ws_size,
                              hipStream_t stream) {
    const float* weight = (const float*)d_in[0];
    const float* maskw  = (const float*)d_in[1];
    const float* pptr   = (const float*)d_in[2];
    float* out = (float*)d_out;
    const long long n = (long long)in_sizes[0];

    unsigned char* ws = (unsigned char*)d_ws;
    unsigned* hist = (unsigned*)ws;
    Ctrl* ctrl = (Ctrl*)(ws + 16384);
    uint2* list = (uint2*)(ws + 16448);
    size_t cap_sz = (ws_size > 16448) ? (ws_size - 16448) / sizeof(uint2) : 0;
    unsigned cap = (unsigned)(cap_sz > (size_t)(1u << 20) ? (1u << 20) : cap_sz);

    k_zero<<<(NBINS + 255) / 256, 256, 0, stream>>>(hist, ctrl);
    k_hist<<<HGRID, HBLK, 0, stream>>>(maskw, n, hist, ctrl, pptr);
    k_apply<<<AGRID, ABLK, 0, stream>>>(weight, maskw, out, n, ctrl, list, cap);
    k_fix<<<1, 256, 0, stream>>>(out, ctrl, list, cap);
}

// Round 14
// 185.438 us; speedup vs baseline: 4.3547x; 1.8563x over previous
//
#include <hip/hip_runtime.h>

#define HIST_BITS 12
#define NBINS (1 << HIST_BITS)        // 4096
#define KEY_SHIFT (32 - HIST_BITS)    // 20
#define REP 4                         // LDS histogram replication factor

typedef float fx4 __attribute__((ext_vector_type(4)));

// ws layout:
//   [0, 16384)     : unsigned hist[4096]
//   [16384, 16416) : Ctrl
//   [16416, ...)   : uint2 candidate list (key, idx)
struct Ctrl {
    long long k;        // number of elements to zero
    long long r1;       // residual rank inside threshold bin (zero first r1)
    int b1;             // threshold bin (-1 => zero nothing)
    unsigned counter;   // candidate list append counter
};

__device__ __forceinline__ unsigned fkey(float f) {
    unsigned u = __float_as_uint(f);
    return (u & 0x80000000u) ? ~u : (u | 0x80000000u);  // monotonic total order
}

// ---------------- K0: zero hist + ctrl ----------------
__global__ void k_zero(unsigned* __restrict__ hist, Ctrl* __restrict__ ctrl) {
    int i = blockIdx.x * blockDim.x + threadIdx.x;
    if (i < NBINS) hist[i] = 0;
    if (i == 0) {
        ctrl->k = 0; ctrl->r1 = 0; ctrl->b1 = -1; ctrl->counter = 0;
    }
}

// ---------------- K1: histogram, block-tiled contiguous, 4-way replicated LDS ----------------
// PURE streaming kernel: no epilogue, no extra arrays. R8/R10/R11/R13 all proved
// that fusing any epilogue here makes the backend squeeze VGPRs (24-32) and
// serialize the ILP4 loop (3-4x slowdown). Keep kernels separated.
__global__ void __launch_bounds__(1024)
k_hist(const float* __restrict__ mask, long long n, unsigned* __restrict__ ghist) {
    __shared__ unsigned sh[NBINS * REP];   // 64 KB: layout bin*REP + r
    for (int i = threadIdx.x; i < NBINS * REP; i += blockDim.x) sh[i] = 0;
    __syncthreads();

    const unsigned r = threadIdx.x & (REP - 1);
    const long long n4 = n >> 2;
    const fx4* m4 = (const fx4*)mask;
    const long long B = blockDim.x;
    const long long per = (n4 + gridDim.x - 1) / gridDim.x;   // fx4 per block (contiguous tile)
    const long long s0 = (long long)blockIdx.x * per;
    const long long e = (s0 + per < n4) ? s0 + per : n4;

    long long i = s0 + threadIdx.x;
    for (; i + 3 * B < e; i += 4 * B) {
        fx4 a = m4[i];
        fx4 b = m4[i + B];
        fx4 c = m4[i + 2 * B];
        fx4 d = m4[i + 3 * B];
        atomicAdd(&sh[(fkey(a.x) >> KEY_SHIFT) * REP + r], 1u);
        atomicAdd(&sh[(fkey(a.y) >> KEY_SHIFT) * REP + r], 1u);
        atomicAdd(&sh[(fkey(a.z) >> KEY_SHIFT) * REP + r], 1u);
        atomicAdd(&sh[(fkey(a.w) >> KEY_SHIFT) * REP + r], 1u);
        atomicAdd(&sh[(fkey(b.x) >> KEY_SHIFT) * REP + r], 1u);
        atomicAdd(&sh[(fkey(b.y) >> KEY_SHIFT) * REP + r], 1u);
        atomicAdd(&sh[(fkey(b.z) >> KEY_SHIFT) * REP + r], 1u);
        atomicAdd(&sh[(fkey(b.w) >> KEY_SHIFT) * REP + r], 1u);
        atomicAdd(&sh[(fkey(c.x) >> KEY_SHIFT) * REP + r], 1u);
        atomicAdd(&sh[(fkey(c.y) >> KEY_SHIFT) * REP + r], 1u);
        atomicAdd(&sh[(fkey(c.z) >> KEY_SHIFT) * REP + r], 1u);
        atomicAdd(&sh[(fkey(c.w) >> KEY_SHIFT) * REP + r], 1u);
        atomicAdd(&sh[(fkey(d.x) >> KEY_SHIFT) * REP + r], 1u);
        atomicAdd(&sh[(fkey(d.y) >> KEY_SHIFT) * REP + r], 1u);
        atomicAdd(&sh[(fkey(d.z) >> KEY_SHIFT) * REP + r], 1u);
        atomicAdd(&sh[(fkey(d.w) >> KEY_SHIFT) * REP + r], 1u);
    }
    for (; i < e; i += B) {
        fx4 a = m4[i];
        atomicAdd(&sh[(fkey(a.x) >> KEY_SHIFT) * REP + r], 1u);
        atomicAdd(&sh[(fkey(a.y) >> KEY_SHIFT) * REP + r], 1u);
        atomicAdd(&sh[(fkey(a.z) >> KEY_SHIFT) * REP + r], 1u);
        atomicAdd(&sh[(fkey(a.w) >> KEY_SHIFT) * REP + r], 1u);
    }
    if (blockIdx.x == 0 && threadIdx.x == 0) {
        for (long long t = n4 * 4; t < n; ++t)
            atomicAdd(&ghist[fkey(mask[t]) >> KEY_SHIFT], 1u);
    }
    __syncthreads();
    for (int b = threadIdx.x; b < NBINS; b += blockDim.x) {
        unsigned s = sh[b * REP] + sh[b * REP + 1] + sh[b * REP + 2] + sh[b * REP + 3];
        if (s) atomicAdd(&ghist[b], s);
    }
}

// ---------------- K2: scan histogram, find threshold bin ----------------
__global__ void k_scan(const unsigned* __restrict__ ghist, Ctrl* __restrict__ ctrl,
                       const float* __restrict__ p_ptr, long long n) {
    __shared__ long long part[256];
    __shared__ long long kk_sh;
    const int t = threadIdx.x;
    if (t == 0) {
        double p = (double)p_ptr[0];
        long long k = (long long)((1.0 - p) * (double)n);  // matches python int()
        if (k < 0) k = 0;
        if (k > n) k = n;
        kk_sh = k;
        ctrl->k = k;
        ctrl->b1 = -1;
        ctrl->r1 = 0;
    }
    __syncthreads();
    const long long k = kk_sh;

    const int per = NBINS / 256;
    long long s = 0;
    for (int i = 0; i < per; ++i) s += (long long)ghist[t * per + i];
    part[t] = s;
    __syncthreads();
    for (int off = 1; off < 256; off <<= 1) {
        long long add = (t >= off) ? part[t - off] : 0;
        __syncthreads();
        part[t] += add;
        __syncthreads();
    }
    if (k >= 1) {
        long long incl = part[t];
        long long excl = incl - s;
        if (excl < k && k <= incl) {
            long long cum = excl;
            for (int i = 0; i < per; ++i) {
                long long c = (long long)ghist[t * per + i];
                if (cum < k && k <= cum + c) {
                    ctrl->b1 = t * per + i;
                    ctrl->r1 = k - cum;
                    break;
                }
                cum += c;
            }
        }
    }
}

// ---------------- K3: fused apply, block-tiled contiguous, ILP4 ----------------
// PURE streaming kernel: no __shared__, no epilogue (see k_hist note).
__device__ __forceinline__ void cand4(unsigned k0, unsigned k1, unsigned k2, unsigned k3,
                                      unsigned base, unsigned b1u,
                                      Ctrl* ctrl, uint2* list, unsigned cap) {
    if ((k0 >> KEY_SHIFT) == b1u) { unsigned p = atomicAdd(&ctrl->counter, 1u); if (p < cap) list[p] = make_uint2(k0, base + 0); }
    if ((k1 >> KEY_SHIFT) == b1u) { unsigned p = atomicAdd(&ctrl->counter, 1u); if (p < cap) list[p] = make_uint2(k1, base + 1); }
    if ((k2 >> KEY_SHIFT) == b1u) { unsigned p = atomicAdd(&ctrl->counter, 1u); if (p < cap) list[p] = make_uint2(k2, base + 2); }
    if ((k3 >> KEY_SHIFT) == b1u) { unsigned p = atomicAdd(&ctrl->counter, 1u); if (p < cap) list[p] = make_uint2(k3, base + 3); }
}

__global__ void __launch_bounds__(256)
k_apply(const float* __restrict__ w, const float* __restrict__ mask,
        float* __restrict__ out, long long n,
        Ctrl* __restrict__ ctrl, uint2* __restrict__ list, unsigned cap) {
    const int b1 = ctrl->b1;
    const unsigned b1u = (unsigned)b1;                                   // ==bin never true for b1=-1
    const unsigned lo = (b1 <= 0) ? 0u : ((unsigned)b1 << KEY_SHIFT);    // keep iff key >= lo
    const long long n4 = n >> 2;
    const fx4* m4 = (const fx4*)mask;
    const fx4* w4 = (const fx4*)w;
    fx4* o4 = (fx4*)out;
    const long long B = blockDim.x;
    const long long per = (n4 + gridDim.x - 1) / gridDim.x;   // fx4 per block (contiguous tile)
    const long long s0 = (long long)blockIdx.x * per;
    const long long e = (s0 + per < n4) ? s0 + per : n4;

    long long i = s0 + threadIdx.x;
    for (; i + 3 * B < e; i += 4 * B) {
        fx4 m0 = m4[i];
        fx4 m1 = m4[i + B];
        fx4 m2 = m4[i + 2 * B];
        fx4 m3 = m4[i + 3 * B];
        fx4 w0 = __builtin_nontemporal_load(&w4[i]);
        fx4 w1 = __builtin_nontemporal_load(&w4[i + B]);
        fx4 w2 = __builtin_nontemporal_load(&w4[i + 2 * B]);
        fx4 w3 = __builtin_nontemporal_load(&w4[i + 3 * B]);
        unsigned k00 = fkey(m0.x), k01 = fkey(m0.y), k02 = fkey(m0.z), k03 = fkey(m0.w);
        unsigned k10 = fkey(m1.x), k11 = fkey(m1.y), k12 = fkey(m1.z), k13 = fkey(m1.w);
        unsigned k20 = fkey(m2.x), k21 = fkey(m2.y), k22 = fkey(m2.z), k23 = fkey(m2.w);
        unsigned k30 = fkey(m3.x), k31 = fkey(m3.y), k32 = fkey(m3.z), k33 = fkey(m3.w);
        fx4 o0, o1, o2, o3;
        o0.x = (k00 >= lo) ? w0.x : 0.0f;  o0.y = (k01 >= lo) ? w0.y : 0.0f;
        o0.z = (k02 >= lo) ? w0.z : 0.0f;  o0.w = (k03 >= lo) ? w0.w : 0.0f;
        o1.x = (k10 >= lo) ? w1.x : 0.0f;  o1.y = (k11 >= lo) ? w1.y : 0.0f;
        o1.z = (k12 >= lo) ? w1.z : 0.0f;  o1.w = (k13 >= lo) ? w1.w : 0.0f;
        o2.x = (k20 >= lo) ? w2.x : 0.0f;  o2.y = (k21 >= lo) ? w2.y : 0.0f;
        o2.z = (k22 >= lo) ? w2.z : 0.0f;  o2.w = (k23 >= lo) ? w2.w : 0.0f;
        o3.x = (k30 >= lo) ? w3.x : 0.0f;  o3.y = (k31 >= lo) ? w3.y : 0.0f;
        o3.z = (k32 >= lo) ? w3.z : 0.0f;  o3.w = (k33 >= lo) ? w3.w : 0.0f;
        __builtin_nontemporal_store(o0, &o4[i]);
        __builtin_nontemporal_store(o1, &o4[i + B]);
        __builtin_nontemporal_store(o2, &o4[i + 2 * B]);
        __builtin_nontemporal_store(o3, &o4[i + 3 * B]);
        // rare: any lane has an element in the threshold bin -> slow path (1 branch/iter)
        bool anyc = ((k00 >> KEY_SHIFT) == b1u) | ((k01 >> KEY_SHIFT) == b1u) |
                    ((k02 >> KEY_SHIFT) == b1u) | ((k03 >> KEY_SHIFT) == b1u) |
                    ((k10 >> KEY_SHIFT) == b1u) | ((k11 >> KEY_SHIFT) == b1u) |
                    ((k12 >> KEY_SHIFT) == b1u) | ((k13 >> KEY_SHIFT) == b1u) |
                    ((k20 >> KEY_SHIFT) == b1u) | ((k21 >> KEY_SHIFT) == b1u) |
                    ((k22 >> KEY_SHIFT) == b1u) | ((k23 >> KEY_SHIFT) == b1u) |
                    ((k30 >> KEY_SHIFT) == b1u) | ((k31 >> KEY_SHIFT) == b1u) |
                    ((k32 >> KEY_SHIFT) == b1u) | ((k33 >> KEY_SHIFT) == b1u);
        if (__any(anyc)) {
            cand4(k00, k01, k02, k03, (unsigned)(i * 4), b1u, ctrl, list, cap);
            cand4(k10, k11, k12, k13, (unsigned)((i + B) * 4), b1u, ctrl, list, cap);
            cand4(k20, k21, k22, k23, (unsigned)((i + 2 * B) * 4), b1u, ctrl, list, cap);
            cand4(k30, k31, k32, k33, (unsigned)((i + 3 * B) * 4), b1u, ctrl, list, cap);
        }
    }
    for (; i < e; i += B) {
        fx4 m0 = m4[i];
        fx4 w0 = __builtin_nontemporal_load(&w4[i]);
        unsigned k00 = fkey(m0.x), k01 = fkey(m0.y), k02 = fkey(m0.z), k03 = fkey(m0.w);
        fx4 o0;
        o0.x = (k00 >= lo) ? w0.x : 0.0f;  o0.y = (k01 >= lo) ? w0.y : 0.0f;
        o0.z = (k02 >= lo) ? w0.z : 0.0f;  o0.w = (k03 >= lo) ? w0.w : 0.0f;
        __builtin_nontemporal_store(o0, &o4[i]);
        bool anyc = ((k00 >> KEY_SHIFT) == b1u) | ((k01 >> KEY_SHIFT) == b1u) |
                    ((k02 >> KEY_SHIFT) == b1u) | ((k03 >> KEY_SHIFT) == b1u);
        if (__any(anyc))
            cand4(k00, k01, k02, k03, (unsigned)(i * 4), b1u, ctrl, list, cap);
    }
    if (blockIdx.x == 0 && threadIdx.x == 0) {
        for (long long t = n4 * 4; t < n; ++t) {
            unsigned key = fkey(mask[t]);
            out[t] = (key >= lo) ? w[t] : 0.0f;
            if ((key >> KEY_SHIFT) == b1u) {
                unsigned p = atomicAdd(&ctrl->counter, 1u);
                if (p < cap) list[p] = make_uint2(key, (unsigned)t);
            }
        }
    }
}

// ---------------- K4: exact rank among candidates, zero first r1 ----------------
__global__ void k_fix(float* __restrict__ out, const Ctrl* __restrict__ ctrl,
                      const uint2* __restrict__ list, unsigned cap) {
    __shared__ uint2 ch[1024];
    unsigned nc = ctrl->counter;
    if (nc > cap) nc = cap;
    const long long r1 = ctrl->r1;
    if (ctrl->b1 < 0 || r1 <= 0) return;

    for (unsigned jb = 0; jb < nc; jb += blockDim.x) {
        unsigned j = jb + threadIdx.x;
        bool act = (j < nc);
        unsigned kj = 0, ij = 0;
        if (act) { uint2 e = list[j]; kj = e.x; ij = e.y; }
        long long rank = 0;
        for (unsigned cb = 0; cb < nc; cb += 1024) {
            unsigned mlen = nc - cb; if (mlen > 1024) mlen = 1024;
            for (unsigned u = threadIdx.x; u < mlen; u += blockDim.x) ch[u] = list[cb + u];
            __syncthreads();
            if (act) {
                for (unsigned u = 0; u < mlen; ++u) {
                    uint2 e = ch[u];
                    rank += (long long)((e.x < kj) || (e.x == kj && e.y < ij));
                }
            }
            __syncthreads();
        }
        if (act && rank < r1) out[ij] = 0.0f;
    }
}

extern "C" void kernel_launch(void* const* d_in, const int* in_sizes, int n_in,
                              void* d_out, int out_size, void* d_ws, size_t ws_size,
                              hipStream_t stream) {
    const float* weight = (const float*)d_in[0];
    const float* maskw  = (const float*)d_in[1];
    const float* pptr   = (const float*)d_in[2];
    float* out = (float*)d_out;
    const long long n = (long long)in_sizes[0];

    unsigned char* ws = (unsigned char*)d_ws;
    unsigned* hist = (unsigned*)ws;
    Ctrl* ctrl = (Ctrl*)(ws + 16384);
    uint2* list = (uint2*)(ws + 16416);
    size_t cap_sz = (ws_size > 16416) ? (ws_size - 16416) / sizeof(uint2) : 0;
    unsigned cap = (unsigned)(cap_sz > (size_t)(1u << 20) ? (1u << 20) : cap_sz);

    k_zero<<<(NBINS + 255) / 256, 256, 0, stream>>>(hist, ctrl);
    k_hist<<<512, 1024, 0, stream>>>(maskw, n, hist);
    k_scan<<<1, 256, 0, stream>>>(hist, ctrl, pptr, n);
    k_apply<<<2048, 256, 0, stream>>>(weight, maskw, out, n, ctrl, list, cap);
    k_fix<<<1, 256, 0, stream>>>(out, ctrl, list, cap);
}

// Round 15
// 184.531 us; speedup vs baseline: 4.3761x; 1.0049x over previous
//
#include <hip/hip_runtime.h>

#define HIST_BITS 12
#define NBINS (1 << HIST_BITS)        // 4096
#define KEY_SHIFT (32 - HIST_BITS)    // 20
#define REP 4                         // LDS histogram replication factor

typedef float fx4 __attribute__((ext_vector_type(4)));

// ws layout:
//   [0, 16384)     : unsigned hist[4096]
//   [16384, 16416) : Ctrl
//   [16416, ...)   : uint2 candidate list (key, idx)
struct Ctrl {
    long long k;        // number of elements to zero
    long long r1;       // residual rank inside threshold bin (zero first r1)
    int b1;             // threshold bin (-1 => zero nothing)
    unsigned counter;   // candidate list append counter
};

__device__ __forceinline__ unsigned fkey(float f) {
    unsigned u = __float_as_uint(f);
    return (u & 0x80000000u) ? ~u : (u | 0x80000000u);  // monotonic total order
}

// ---------------- K0: zero hist + ctrl ----------------
__global__ void k_zero(unsigned* __restrict__ hist, Ctrl* __restrict__ ctrl) {
    int i = blockIdx.x * blockDim.x + threadIdx.x;
    if (i < NBINS) hist[i] = 0;
    if (i == 0) {
        ctrl->k = 0; ctrl->r1 = 0; ctrl->b1 = -1; ctrl->counter = 0;
    }
}

// ---------------- K1: histogram, block-tiled contiguous, 4-way replicated LDS ----------------
// PURE streaming kernel: no epilogue, no extra arrays. R8/R10/R11/R13 all proved
// that fusing any epilogue here makes the backend squeeze VGPRs (24-32) and
// serialize the ILP4 loop (3-4x slowdown). Keep kernels separated.
__global__ void __launch_bounds__(1024)
k_hist(const float* __restrict__ mask, long long n, unsigned* __restrict__ ghist) {
    __shared__ unsigned sh[NBINS * REP];   // 64 KB: layout bin*REP + r
    for (int i = threadIdx.x; i < NBINS * REP; i += blockDim.x) sh[i] = 0;
    __syncthreads();

    const unsigned r = threadIdx.x & (REP - 1);
    const long long n4 = n >> 2;
    const fx4* m4 = (const fx4*)mask;
    const long long B = blockDim.x;
    const long long per = (n4 + gridDim.x - 1) / gridDim.x;   // fx4 per block (contiguous tile)
    const long long s0 = (long long)blockIdx.x * per;
    const long long e = (s0 + per < n4) ? s0 + per : n4;

    long long i = s0 + threadIdx.x;
    for (; i + 3 * B < e; i += 4 * B) {
        fx4 a = m4[i];
        fx4 b = m4[i + B];
        fx4 c = m4[i + 2 * B];
        fx4 d = m4[i + 3 * B];
        atomicAdd(&sh[(fkey(a.x) >> KEY_SHIFT) * REP + r], 1u);
        atomicAdd(&sh[(fkey(a.y) >> KEY_SHIFT) * REP + r], 1u);
        atomicAdd(&sh[(fkey(a.z) >> KEY_SHIFT) * REP + r], 1u);
        atomicAdd(&sh[(fkey(a.w) >> KEY_SHIFT) * REP + r], 1u);
        atomicAdd(&sh[(fkey(b.x) >> KEY_SHIFT) * REP + r], 1u);
        atomicAdd(&sh[(fkey(b.y) >> KEY_SHIFT) * REP + r], 1u);
        atomicAdd(&sh[(fkey(b.z) >> KEY_SHIFT) * REP + r], 1u);
        atomicAdd(&sh[(fkey(b.w) >> KEY_SHIFT) * REP + r], 1u);
        atomicAdd(&sh[(fkey(c.x) >> KEY_SHIFT) * REP + r], 1u);
        atomicAdd(&sh[(fkey(c.y) >> KEY_SHIFT) * REP + r], 1u);
        atomicAdd(&sh[(fkey(c.z) >> KEY_SHIFT) * REP + r], 1u);
        atomicAdd(&sh[(fkey(c.w) >> KEY_SHIFT) * REP + r], 1u);
        atomicAdd(&sh[(fkey(d.x) >> KEY_SHIFT) * REP + r], 1u);
        atomicAdd(&sh[(fkey(d.y) >> KEY_SHIFT) * REP + r], 1u);
        atomicAdd(&sh[(fkey(d.z) >> KEY_SHIFT) * REP + r], 1u);
        atomicAdd(&sh[(fkey(d.w) >> KEY_SHIFT) * REP + r], 1u);
    }
    for (; i < e; i += B) {
        fx4 a = m4[i];
        atomicAdd(&sh[(fkey(a.x) >> KEY_SHIFT) * REP + r], 1u);
        atomicAdd(&sh[(fkey(a.y) >> KEY_SHIFT) * REP + r], 1u);
        atomicAdd(&sh[(fkey(a.z) >> KEY_SHIFT) * REP + r], 1u);
        atomicAdd(&sh[(fkey(a.w) >> KEY_SHIFT) * REP + r], 1u);
    }
    if (blockIdx.x == 0 && threadIdx.x == 0) {
        for (long long t = n4 * 4; t < n; ++t)
            atomicAdd(&ghist[fkey(mask[t]) >> KEY_SHIFT], 1u);
    }
    __syncthreads();
    for (int b = threadIdx.x; b < NBINS; b += blockDim.x) {
        unsigned s = sh[b * REP] + sh[b * REP + 1] + sh[b * REP + 2] + sh[b * REP + 3];
        if (s) atomicAdd(&ghist[b], s);
    }
}

// ---------------- K2: scan histogram, find threshold bin ----------------
__global__ void k_scan(const unsigned* __restrict__ ghist, Ctrl* __restrict__ ctrl,
                       const float* __restrict__ p_ptr, long long n) {
    __shared__ long long part[256];
    __shared__ long long kk_sh;
    const int t = threadIdx.x;
    if (t == 0) {
        double p = (double)p_ptr[0];
        long long k = (long long)((1.0 - p) * (double)n);  // matches python int()
        if (k < 0) k = 0;
        if (k > n) k = n;
        kk_sh = k;
        ctrl->k = k;
        ctrl->b1 = -1;
        ctrl->r1 = 0;
    }
    __syncthreads();
    const long long k = kk_sh;

    const int per = NBINS / 256;
    long long s = 0;
    for (int i = 0; i < per; ++i) s += (long long)ghist[t * per + i];
    part[t] = s;
    __syncthreads();
    for (int off = 1; off < 256; off <<= 1) {
        long long add = (t >= off) ? part[t - off] : 0;
        __syncthreads();
        part[t] += add;
        __syncthreads();
    }
    if (k >= 1) {
        long long incl = part[t];
        long long excl = incl - s;
        if (excl < k && k <= incl) {
            long long cum = excl;
            for (int i = 0; i < per; ++i) {
                long long c = (long long)ghist[t * per + i];
                if (cum < k && k <= cum + c) {
                    ctrl->b1 = t * per + i;
                    ctrl->r1 = k - cum;
                    break;
                }
                cum += c;
            }
        }
    }
}

// ---------------- K3: fused apply, block-tiled contiguous, ILP4 ----------------
// PURE streaming kernel: no __shared__, no epilogue (see k_hist note).
__device__ __forceinline__ void cand4(unsigned k0, unsigned k1, unsigned k2, unsigned k3,
                                      unsigned base, unsigned b1u,
                                      Ctrl* ctrl, uint2* list, unsigned cap) {
    if ((k0 >> KEY_SHIFT) == b1u) { unsigned p = atomicAdd(&ctrl->counter, 1u); if (p < cap) list[p] = make_uint2(k0, base + 0); }
    if ((k1 >> KEY_SHIFT) == b1u) { unsigned p = atomicAdd(&ctrl->counter, 1u); if (p < cap) list[p] = make_uint2(k1, base + 1); }
    if ((k2 >> KEY_SHIFT) == b1u) { unsigned p = atomicAdd(&ctrl->counter, 1u); if (p < cap) list[p] = make_uint2(k2, base + 2); }
    if ((k3 >> KEY_SHIFT) == b1u) { unsigned p = atomicAdd(&ctrl->counter, 1u); if (p < cap) list[p] = make_uint2(k3, base + 3); }
}

__global__ void __launch_bounds__(256)
k_apply(const float* __restrict__ w, const float* __restrict__ mask,
        float* __restrict__ out, long long n,
        Ctrl* __restrict__ ctrl, uint2* __restrict__ list, unsigned cap) {
    const int b1 = ctrl->b1;
    const unsigned b1u = (unsigned)b1;                                   // ==bin never true for b1=-1
    const unsigned lo = (b1 <= 0) ? 0u : ((unsigned)b1 << KEY_SHIFT);    // keep iff key >= lo
    const long long n4 = n >> 2;
    const fx4* m4 = (const fx4*)mask;
    const fx4* w4 = (const fx4*)w;
    fx4* o4 = (fx4*)out;
    const long long B = blockDim.x;
    const long long per = (n4 + gridDim.x - 1) / gridDim.x;   // fx4 per block (contiguous tile)
    const long long s0 = (long long)blockIdx.x * per;
    const long long e = (s0 + per < n4) ? s0 + per : n4;

    long long i = s0 + threadIdx.x;
    for (; i + 3 * B < e; i += 4 * B) {
        fx4 m0 = m4[i];
        fx4 m1 = m4[i + B];
        fx4 m2 = m4[i + 2 * B];
        fx4 m3 = m4[i + 3 * B];
        fx4 w0 = __builtin_nontemporal_load(&w4[i]);
        fx4 w1 = __builtin_nontemporal_load(&w4[i + B]);
        fx4 w2 = __builtin_nontemporal_load(&w4[i + 2 * B]);
        fx4 w3 = __builtin_nontemporal_load(&w4[i + 3 * B]);
        unsigned k00 = fkey(m0.x), k01 = fkey(m0.y), k02 = fkey(m0.z), k03 = fkey(m0.w);
        unsigned k10 = fkey(m1.x), k11 = fkey(m1.y), k12 = fkey(m1.z), k13 = fkey(m1.w);
        unsigned k20 = fkey(m2.x), k21 = fkey(m2.y), k22 = fkey(m2.z), k23 = fkey(m2.w);
        unsigned k30 = fkey(m3.x), k31 = fkey(m3.y), k32 = fkey(m3.z), k33 = fkey(m3.w);
        fx4 o0, o1, o2, o3;
        o0.x = (k00 >= lo) ? w0.x : 0.0f;  o0.y = (k01 >= lo) ? w0.y : 0.0f;
        o0.z = (k02 >= lo) ? w0.z : 0.0f;  o0.w = (k03 >= lo) ? w0.w : 0.0f;
        o1.x = (k10 >= lo) ? w1.x : 0.0f;  o1.y = (k11 >= lo) ? w1.y : 0.0f;
        o1.z = (k12 >= lo) ? w1.z : 0.0f;  o1.w = (k13 >= lo) ? w1.w : 0.0f;
        o2.x = (k20 >= lo) ? w2.x : 0.0f;  o2.y = (k21 >= lo) ? w2.y : 0.0f;
        o2.z = (k22 >= lo) ? w2.z : 0.0f;  o2.w = (k23 >= lo) ? w2.w : 0.0f;
        o3.x = (k30 >= lo) ? w3.x : 0.0f;  o3.y = (k31 >= lo) ? w3.y : 0.0f;
        o3.z = (k32 >= lo) ? w3.z : 0.0f;  o3.w = (k33 >= lo) ? w3.w : 0.0f;
        __builtin_nontemporal_store(o0, &o4[i]);
        __builtin_nontemporal_store(o1, &o4[i + B]);
        __builtin_nontemporal_store(o2, &o4[i + 2 * B]);
        __builtin_nontemporal_store(o3, &o4[i + 3 * B]);
        // rare: any lane has an element in the threshold bin -> slow path (1 branch/iter)
        bool anyc = ((k00 >> KEY_SHIFT) == b1u) | ((k01 >> KEY_SHIFT) == b1u) |
                    ((k02 >> KEY_SHIFT) == b1u) | ((k03 >> KEY_SHIFT) == b1u) |
                    ((k10 >> KEY_SHIFT) == b1u) | ((k11 >> KEY_SHIFT) == b1u) |
                    ((k12 >> KEY_SHIFT) == b1u) | ((k13 >> KEY_SHIFT) == b1u) |
                    ((k20 >> KEY_SHIFT) == b1u) | ((k21 >> KEY_SHIFT) == b1u) |
                    ((k22 >> KEY_SHIFT) == b1u) | ((k23 >> KEY_SHIFT) == b1u) |
                    ((k30 >> KEY_SHIFT) == b1u) | ((k31 >> KEY_SHIFT) == b1u) |
                    ((k32 >> KEY_SHIFT) == b1u) | ((k33 >> KEY_SHIFT) == b1u);
        if (__any(anyc)) {
            cand4(k00, k01, k02, k03, (unsigned)(i * 4), b1u, ctrl, list, cap);
            cand4(k10, k11, k12, k13, (unsigned)((i + B) * 4), b1u, ctrl, list, cap);
            cand4(k20, k21, k22, k23, (unsigned)((i + 2 * B) * 4), b1u, ctrl, list, cap);
            cand4(k30, k31, k32, k33, (unsigned)((i + 3 * B) * 4), b1u, ctrl, list, cap);
        }
    }
    for (; i < e; i += B) {
        fx4 m0 = m4[i];
        fx4 w0 = __builtin_nontemporal_load(&w4[i]);
        unsigned k00 = fkey(m0.x), k01 = fkey(m0.y), k02 = fkey(m0.z), k03 = fkey(m0.w);
        fx4 o0;
        o0.x = (k00 >= lo) ? w0.x : 0.0f;  o0.y = (k01 >= lo) ? w0.y : 0.0f;
        o0.z = (k02 >= lo) ? w0.z : 0.0f;  o0.w = (k03 >= lo) ? w0.w : 0.0f;
        __builtin_nontemporal_store(o0, &o4[i]);
        bool anyc = ((k00 >> KEY_SHIFT) == b1u) | ((k01 >> KEY_SHIFT) == b1u) |
                    ((k02 >> KEY_SHIFT) == b1u) | ((k03 >> KEY_SHIFT) == b1u);
        if (__any(anyc))
            cand4(k00, k01, k02, k03, (unsigned)(i * 4), b1u, ctrl, list, cap);
    }
    if (blockIdx.x == 0 && threadIdx.x == 0) {
        for (long long t = n4 * 4; t < n; ++t) {
            unsigned key = fkey(mask[t]);
            out[t] = (key >= lo) ? w[t] : 0.0f;
            if ((key >> KEY_SHIFT) == b1u) {
                unsigned p = atomicAdd(&ctrl->counter, 1u);
                if (p < cap) list[p] = make_uint2(key, (unsigned)t);
            }
        }
    }
}

// ---------------- K4: exact rank among candidates, zero first r1 ----------------
__global__ void k_fix(float* __restrict__ out, const Ctrl* __restrict__ ctrl,
                      const uint2* __restrict__ list, unsigned cap) {
    __shared__ uint2 ch[1024];
    unsigned nc = ctrl->counter;
    if (nc > cap) nc = cap;
    const long long r1 = ctrl->r1;
    if (ctrl->b1 < 0 || r1 <= 0) return;

    for (unsigned jb = 0; jb < nc; jb += blockDim.x) {
        unsigned j = jb + threadIdx.x;
        bool act = (j < nc);
        unsigned kj = 0, ij = 0;
        if (act) { uint2 e = list[j]; kj = e.x; ij = e.y; }
        long long rank = 0;
        for (unsigned cb = 0; cb < nc; cb += 1024) {
            unsigned mlen = nc - cb; if (mlen > 1024) mlen = 1024;
            for (unsigned u = threadIdx.x; u < mlen; u += blockDim.x) ch[u] = list[cb + u];
            __syncthreads();
            if (act) {
                for (unsigned u = 0; u < mlen; ++u) {
                    uint2 e = ch[u];
                    rank += (long long)((e.x < kj) || (e.x == kj && e.y < ij));
                }
            }
            __syncthreads();
        }
        if (act && rank < r1) out[ij] = 0.0f;
    }
}

extern "C" void kernel_launch(void* const* d_in, const int* in_sizes, int n_in,
                              void* d_out, int out_size, void* d_ws, size_t ws_size,
                              hipStream_t stream) {
    const float* weight = (const float*)d_in[0];
    const float* maskw  = (const float*)d_in[1];
    const float* pptr   = (const float*)d_in[2];
    float* out = (float*)d_out;
    const long long n = (long long)in_sizes[0];

    unsigned char* ws = (unsigned char*)d_ws;
    unsigned* hist = (unsigned*)ws;
    Ctrl* ctrl = (Ctrl*)(ws + 16384);
    uint2* list = (uint2*)(ws + 16416);
    size_t cap_sz = (ws_size > 16416) ? (ws_size - 16416) / sizeof(uint2) : 0;
    unsigned cap = (unsigned)(cap_sz > (size_t)(1u << 20) ? (1u << 20) : cap_sz);

    k_zero<<<(NBINS + 255) / 256, 256, 0, stream>>>(hist, ctrl);
    k_hist<<<512, 1024, 0, stream>>>(maskw, n, hist);
    k_scan<<<1, 256, 0, stream>>>(hist, ctrl, pptr, n);
    k_apply<<<2048, 256, 0, stream>>>(weight, maskw, out, n, ctrl, list, cap);
    k_fix<<<1, 256, 0, stream>>>(out, ctrl, list, cap);
}

// Round 16
// 181.836 us; speedup vs baseline: 4.4410x; 1.0148x over previous
//
#include <hip/hip_runtime.h>

#define HIST_BITS 12
#define NBINS (1 << HIST_BITS)        // 4096
#define KEY_SHIFT (32 - HIST_BITS)    // 20
#define REP 4                         // LDS histogram replication factor

typedef float fx4 __attribute__((ext_vector_type(4)));

// ws layout:
//   [0, 16384)     : unsigned hist[4096]
//   [16384, 16416) : Ctrl
//   [16416, ...)   : uint2 candidate list (key, idx)
struct Ctrl {
    long long k;        // number of elements to zero
    long long r1;       // residual rank inside threshold bin (zero first r1)
    int b1;             // threshold bin (-1 => zero nothing)
    unsigned counter;   // candidate list append counter
};

__device__ __forceinline__ unsigned fkey(float f) {
    unsigned u = __float_as_uint(f);
    return (u & 0x80000000u) ? ~u : (u | 0x80000000u);  // monotonic total order
}

// ---------------- K0: zero hist + ctrl ----------------
__global__ void k_zero(unsigned* __restrict__ hist, Ctrl* __restrict__ ctrl) {
    int i = blockIdx.x * blockDim.x + threadIdx.x;
    if (i < NBINS) hist[i] = 0;
    if (i == 0) {
        ctrl->k = 0; ctrl->r1 = 0; ctrl->b1 = -1; ctrl->counter = 0;
    }
}

// ---------------- K1: histogram, block-tiled contiguous, 4-way replicated LDS ----------------
// PURE streaming kernel: no epilogue (R8/R10/R11/R13: fused epilogues squeeze VGPRs
// to 24-32 and serialize the loop). sched_barrier(0) after the 4 loads forces all
// four to be in flight before any atomic consumes them (anti-serialization).
__global__ void __launch_bounds__(1024)
k_hist(const float* __restrict__ mask, long long n, unsigned* __restrict__ ghist) {
    __shared__ unsigned sh[NBINS * REP];   // 64 KB: layout bin*REP + r
    for (int i = threadIdx.x; i < NBINS * REP; i += blockDim.x) sh[i] = 0;
    __syncthreads();

    const unsigned r = threadIdx.x & (REP - 1);
    const long long n4 = n >> 2;
    const fx4* m4 = (const fx4*)mask;
    const long long B = blockDim.x;
    const long long per = (n4 + gridDim.x - 1) / gridDim.x;   // fx4 per block (contiguous tile)
    const long long s0 = (long long)blockIdx.x * per;
    const long long e = (s0 + per < n4) ? s0 + per : n4;

    long long i = s0 + threadIdx.x;
    for (; i + 3 * B < e; i += 4 * B) {
        fx4 a = m4[i];
        fx4 b = m4[i + B];
        fx4 c = m4[i + 2 * B];
        fx4 d = m4[i + 3 * B];
        __builtin_amdgcn_sched_barrier(0);   // all 4 loads issued before any consumer
        atomicAdd(&sh[(fkey(a.x) >> KEY_SHIFT) * REP + r], 1u);
        atomicAdd(&sh[(fkey(a.y) >> KEY_SHIFT) * REP + r], 1u);
        atomicAdd(&sh[(fkey(a.z) >> KEY_SHIFT) * REP + r], 1u);
        atomicAdd(&sh[(fkey(a.w) >> KEY_SHIFT) * REP + r], 1u);
        atomicAdd(&sh[(fkey(b.x) >> KEY_SHIFT) * REP + r], 1u);
        atomicAdd(&sh[(fkey(b.y) >> KEY_SHIFT) * REP + r], 1u);
        atomicAdd(&sh[(fkey(b.z) >> KEY_SHIFT) * REP + r], 1u);
        atomicAdd(&sh[(fkey(b.w) >> KEY_SHIFT) * REP + r], 1u);
        atomicAdd(&sh[(fkey(c.x) >> KEY_SHIFT) * REP + r], 1u);
        atomicAdd(&sh[(fkey(c.y) >> KEY_SHIFT) * REP + r], 1u);
        atomicAdd(&sh[(fkey(c.z) >> KEY_SHIFT) * REP + r], 1u);
        atomicAdd(&sh[(fkey(c.w) >> KEY_SHIFT) * REP + r], 1u);
        atomicAdd(&sh[(fkey(d.x) >> KEY_SHIFT) * REP + r], 1u);
        atomicAdd(&sh[(fkey(d.y) >> KEY_SHIFT) * REP + r], 1u);
        atomicAdd(&sh[(fkey(d.z) >> KEY_SHIFT) * REP + r], 1u);
        atomicAdd(&sh[(fkey(d.w) >> KEY_SHIFT) * REP + r], 1u);
    }
    for (; i < e; i += B) {
        fx4 a = m4[i];
        atomicAdd(&sh[(fkey(a.x) >> KEY_SHIFT) * REP + r], 1u);
        atomicAdd(&sh[(fkey(a.y) >> KEY_SHIFT) * REP + r], 1u);
        atomicAdd(&sh[(fkey(a.z) >> KEY_SHIFT) * REP + r], 1u);
        atomicAdd(&sh[(fkey(a.w) >> KEY_SHIFT) * REP + r], 1u);
    }
    if (blockIdx.x == 0 && threadIdx.x == 0) {
        for (long long t = n4 * 4; t < n; ++t)
            atomicAdd(&ghist[fkey(mask[t]) >> KEY_SHIFT], 1u);
    }
    __syncthreads();
    for (int b = threadIdx.x; b < NBINS; b += blockDim.x) {
        unsigned s = sh[b * REP] + sh[b * REP + 1] + sh[b * REP + 2] + sh[b * REP + 3];
        if (s) atomicAdd(&ghist[b], s);
    }
}

// ---------------- K2: scan histogram, find threshold bin ----------------
__global__ void k_scan(const unsigned* __restrict__ ghist, Ctrl* __restrict__ ctrl,
                       const float* __restrict__ p_ptr, long long n) {
    __shared__ long long part[256];
    __shared__ long long kk_sh;
    const int t = threadIdx.x;
    if (t == 0) {
        double p = (double)p_ptr[0];
        long long k = (long long)((1.0 - p) * (double)n);  // matches python int()
        if (k < 0) k = 0;
        if (k > n) k = n;
        kk_sh = k;
        ctrl->k = k;
        ctrl->b1 = -1;
        ctrl->r1 = 0;
    }
    __syncthreads();
    const long long k = kk_sh;

    const int per = NBINS / 256;
    long long s = 0;
    for (int i = 0; i < per; ++i) s += (long long)ghist[t * per + i];
    part[t] = s;
    __syncthreads();
    for (int off = 1; off < 256; off <<= 1) {
        long long add = (t >= off) ? part[t - off] : 0;
        __syncthreads();
        part[t] += add;
        __syncthreads();
    }
    if (k >= 1) {
        long long incl = part[t];
        long long excl = incl - s;
        if (excl < k && k <= incl) {
            long long cum = excl;
            for (int i = 0; i < per; ++i) {
                long long c = (long long)ghist[t * per + i];
                if (cum < k && k <= cum + c) {
                    ctrl->b1 = t * per + i;
                    ctrl->r1 = k - cum;
                    break;
                }
                cum += c;
            }
        }
    }
}

// ---------------- K3: fused apply, block-tiled contiguous, ILP4 + forced MLP ----------------
// PURE streaming kernel: no __shared__, no epilogue (see k_hist note). sched_barrier(0)
// after the 8 loads forces all of them in flight (R2 evidence: VGPR_Count=12 meant the
// allocator had serialized the "parallel" loads).
__device__ __forceinline__ void cand4(unsigned k0, unsigned k1, unsigned k2, unsigned k3,
                                      unsigned base, unsigned b1u,
                                      Ctrl* ctrl, uint2* list, unsigned cap) {
    if ((k0 >> KEY_SHIFT) == b1u) { unsigned p = atomicAdd(&ctrl->counter, 1u); if (p < cap) list[p] = make_uint2(k0, base + 0); }
    if ((k1 >> KEY_SHIFT) == b1u) { unsigned p = atomicAdd(&ctrl->counter, 1u); if (p < cap) list[p] = make_uint2(k1, base + 1); }
    if ((k2 >> KEY_SHIFT) == b1u) { unsigned p = atomicAdd(&ctrl->counter, 1u); if (p < cap) list[p] = make_uint2(k2, base + 2); }
    if ((k3 >> KEY_SHIFT) == b1u) { unsigned p = atomicAdd(&ctrl->counter, 1u); if (p < cap) list[p] = make_uint2(k3, base + 3); }
}

__global__ void __launch_bounds__(256)
k_apply(const float* __restrict__ w, const float* __restrict__ mask,
        float* __restrict__ out, long long n,
        Ctrl* __restrict__ ctrl, uint2* __restrict__ list, unsigned cap) {
    const int b1 = ctrl->b1;
    const unsigned b1u = (unsigned)b1;                                   // ==bin never true for b1=-1
    const unsigned lo = (b1 <= 0) ? 0u : ((unsigned)b1 << KEY_SHIFT);    // keep iff key >= lo
    const long long n4 = n >> 2;
    const fx4* m4 = (const fx4*)mask;
    const fx4* w4 = (const fx4*)w;
    fx4* o4 = (fx4*)out;
    const long long B = blockDim.x;
    const long long per = (n4 + gridDim.x - 1) / gridDim.x;   // fx4 per block (contiguous tile)
    const long long s0 = (long long)blockIdx.x * per;
    const long long e = (s0 + per < n4) ? s0 + per : n4;

    long long i = s0 + threadIdx.x;
    for (; i + 3 * B < e; i += 4 * B) {
        fx4 m0 = m4[i];
        fx4 m1 = m4[i + B];
        fx4 m2 = m4[i + 2 * B];
        fx4 m3 = m4[i + 3 * B];
        fx4 w0 = __builtin_nontemporal_load(&w4[i]);
        fx4 w1 = __builtin_nontemporal_load(&w4[i + B]);
        fx4 w2 = __builtin_nontemporal_load(&w4[i + 2 * B]);
        fx4 w3 = __builtin_nontemporal_load(&w4[i + 3 * B]);
        __builtin_amdgcn_sched_barrier(0);   // all 8 loads issued before any consumer
        unsigned k00 = fkey(m0.x), k01 = fkey(m0.y), k02 = fkey(m0.z), k03 = fkey(m0.w);
        unsigned k10 = fkey(m1.x), k11 = fkey(m1.y), k12 = fkey(m1.z), k13 = fkey(m1.w);
        unsigned k20 = fkey(m2.x), k21 = fkey(m2.y), k22 = fkey(m2.z), k23 = fkey(m2.w);
        unsigned k30 = fkey(m3.x), k31 = fkey(m3.y), k32 = fkey(m3.z), k33 = fkey(m3.w);
        fx4 o0, o1, o2, o3;
        o0.x = (k00 >= lo) ? w0.x : 0.0f;  o0.y = (k01 >= lo) ? w0.y : 0.0f;
        o0.z = (k02 >= lo) ? w0.z : 0.0f;  o0.w = (k03 >= lo) ? w0.w : 0.0f;
        o1.x = (k10 >= lo) ? w1.x : 0.0f;  o1.y = (k11 >= lo) ? w1.y : 0.0f;
        o1.z = (k12 >= lo) ? w1.z : 0.0f;  o1.w = (k13 >= lo) ? w1.w : 0.0f;
        o2.x = (k20 >= lo) ? w2.x : 0.0f;  o2.y = (k21 >= lo) ? w2.y : 0.0f;
        o2.z = (k22 >= lo) ? w2.z : 0.0f;  o2.w = (k23 >= lo) ? w2.w : 0.0f;
        o3.x = (k30 >= lo) ? w3.x : 0.0f;  o3.y = (k31 >= lo) ? w3.y : 0.0f;
        o3.z = (k32 >= lo) ? w3.z : 0.0f;  o3.w = (k33 >= lo) ? w3.w : 0.0f;
        __builtin_nontemporal_store(o0, &o4[i]);
        __builtin_nontemporal_store(o1, &o4[i + B]);
        __builtin_nontemporal_store(o2, &o4[i + 2 * B]);
        __builtin_nontemporal_store(o3, &o4[i + 3 * B]);
        // rare: any lane has an element in the threshold bin -> slow path (1 branch/iter)
        bool anyc = ((k00 >> KEY_SHIFT) == b1u) | ((k01 >> KEY_SHIFT) == b1u) |
                    ((k02 >> KEY_SHIFT) == b1u) | ((k03 >> KEY_SHIFT) == b1u) |
                    ((k10 >> KEY_SHIFT) == b1u) | ((k11 >> KEY_SHIFT) == b1u) |
                    ((k12 >> KEY_SHIFT) == b1u) | ((k13 >> KEY_SHIFT) == b1u) |
                    ((k20 >> KEY_SHIFT) == b1u) | ((k21 >> KEY_SHIFT) == b1u) |
                    ((k22 >> KEY_SHIFT) == b1u) | ((k23 >> KEY_SHIFT) == b1u) |
                    ((k30 >> KEY_SHIFT) == b1u) | ((k31 >> KEY_SHIFT) == b1u) |
                    ((k32 >> KEY_SHIFT) == b1u) | ((k33 >> KEY_SHIFT) == b1u);
        if (__any(anyc)) {
            cand4(k00, k01, k02, k03, (unsigned)(i * 4), b1u, ctrl, list, cap);
            cand4(k10, k11, k12, k13, (unsigned)((i + B) * 4), b1u, ctrl, list, cap);
            cand4(k20, k21, k22, k23, (unsigned)((i + 2 * B) * 4), b1u, ctrl, list, cap);
            cand4(k30, k31, k32, k33, (unsigned)((i + 3 * B) * 4), b1u, ctrl, list, cap);
        }
    }
    for (; i < e; i += B) {
        fx4 m0 = m4[i];
        fx4 w0 = __builtin_nontemporal_load(&w4[i]);
        unsigned k00 = fkey(m0.x), k01 = fkey(m0.y), k02 = fkey(m0.z), k03 = fkey(m0.w);
        fx4 o0;
        o0.x = (k00 >= lo) ? w0.x : 0.0f;  o0.y = (k01 >= lo) ? w0.y : 0.0f;
        o0.z = (k02 >= lo) ? w0.z : 0.0f;  o0.w = (k03 >= lo) ? w0.w : 0.0f;
        __builtin_nontemporal_store(o0, &o4[i]);
        bool anyc = ((k00 >> KEY_SHIFT) == b1u) | ((k01 >> KEY_SHIFT) == b1u) |
                    ((k02 >> KEY_SHIFT) == b1u) | ((k03 >> KEY_SHIFT) == b1u);
        if (__any(anyc))
            cand4(k00, k01, k02, k03, (unsigned)(i * 4), b1u, ctrl, list, cap);
    }
    if (blockIdx.x == 0 && threadIdx.x == 0) {
        for (long long t = n4 * 4; t < n; ++t) {
            unsigned key = fkey(mask[t]);
            out[t] = (key >= lo) ? w[t] : 0.0f;
            if ((key >> KEY_SHIFT) == b1u) {
                unsigned p = atomicAdd(&ctrl->counter, 1u);
                if (p < cap) list[p] = make_uint2(key, (unsigned)t);
            }
        }
    }
}

// ---------------- K4: exact rank among candidates, zero first r1 ----------------
__global__ void k_fix(float* __restrict__ out, const Ctrl* __restrict__ ctrl,
                      const uint2* __restrict__ list, unsigned cap) {
    __shared__ uint2 ch[1024];
    unsigned nc = ctrl->counter;
    if (nc > cap) nc = cap;
    const long long r1 = ctrl->r1;
    if (ctrl->b1 < 0 || r1 <= 0) return;

    for (unsigned jb = 0; jb < nc; jb += blockDim.x) {
        unsigned j = jb + threadIdx.x;
        bool act = (j < nc);
        unsigned kj = 0, ij = 0;
        if (act) { uint2 e = list[j]; kj = e.x; ij = e.y; }
        long long rank = 0;
        for (unsigned cb = 0; cb < nc; cb += 1024) {
            unsigned mlen = nc - cb; if (mlen > 1024) mlen = 1024;
            for (unsigned u = threadIdx.x; u < mlen; u += blockDim.x) ch[u] = list[cb + u];
            __syncthreads();
            if (act) {
                for (unsigned u = 0; u < mlen; ++u) {
                    uint2 e = ch[u];
                    rank += (long long)((e.x < kj) || (e.x == kj && e.y < ij));
                }
            }
            __syncthreads();
        }
        if (act && rank < r1) out[ij] = 0.0f;
    }
}

extern "C" void kernel_launch(void* const* d_in, const int* in_sizes, int n_in,
                              void* d_out, int out_size, void* d_ws, size_t ws_size,
                              hipStream_t stream) {
    const float* weight = (const float*)d_in[0];
    const float* maskw  = (const float*)d_in[1];
    const float* pptr   = (const float*)d_in[2];
    float* out = (float*)d_out;
    const long long n = (long long)in_sizes[0];

    unsigned char* ws = (unsigned char*)d_ws;
    unsigned* hist = (unsigned*)ws;
    Ctrl* ctrl = (Ctrl*)(ws + 16384);
    uint2* list = (uint2*)(ws + 16416);
    size_t cap_sz = (ws_size > 16416) ? (ws_size - 16416) / sizeof(uint2) : 0;
    unsigned cap = (unsigned)(cap_sz > (size_t)(1u << 20) ? (1u << 20) : cap_sz);

    k_zero<<<(NBINS + 255) / 256, 256, 0, stream>>>(hist, ctrl);
    k_hist<<<512, 1024, 0, stream>>>(maskw, n, hist);
    k_scan<<<1, 256, 0, stream>>>(hist, ctrl, pptr, n);
    k_apply<<<2048, 256, 0, stream>>>(weight, maskw, out, n, ctrl, list, cap);
    k_fix<<<1, 256, 0, stream>>>(out, ctrl, list, cap);
}